// Round 1
// baseline (10632.020 us; speedup 1.0000x reference)
//
#include <hip/hip_runtime.h>
#include <math.h>

#define B_   128
#define T_   512
#define Z_   32
#define AD_  16
#define K_   8

#define OSTRIDE 2112   // per (b,t): fm(32) fc(1024) sm(32) sc(1024)
#define OFF_FM  0
#define OFF_FC  32
#define OFF_SM  1056
#define OFF_SC  1088

#define ZS   36   // padded row stride for 32-wide LDS rows (mult of 4 -> float4 aligned)
#define CTS  20   // CmixT row stride (16 cols)
#define AW   68   // GJ32 augmented stride
#define A16W 52   // GJ16 augmented stride

typedef float4 f4;

__device__ __forceinline__ f4 g4(const float* p) { return *reinterpret_cast<const f4*>(p); }
__device__ __forceinline__ void s4(float* p, f4 v) { *reinterpret_cast<f4*>(p) = v; }
__device__ __forceinline__ f4 zero4() { return make_float4(0.f, 0.f, 0.f, 0.f); }
__device__ __forceinline__ f4 fma4(float a, f4 b, f4 c) {
    c.x = fmaf(a, b.x, c.x); c.y = fmaf(a, b.y, c.y);
    c.z = fmaf(a, b.z, c.z); c.w = fmaf(a, b.w, c.w);
    return c;
}
__device__ __forceinline__ f4 fnma4(float a, f4 b, f4 c) {  // c - a*b
    c.x = fmaf(-a, b.x, c.x); c.y = fmaf(-a, b.y, c.y);
    c.z = fmaf(-a, b.z, c.z); c.w = fmaf(-a, b.w, c.w);
    return c;
}
__device__ __forceinline__ f4 sub4(f4 a, f4 b) {
    return make_float4(a.x - b.x, a.y - b.y, a.z - b.z, a.w - b.w);
}

__global__ __launch_bounds__(256, 1) void kalman(
    const float* __restrict__ g_a,     // [B,T,16]
    const float* __restrict__ g_alpha, // [B,T,8]
    const float* __restrict__ g_u,     // [B,T,32]
    const float* __restrict__ gA,      // [8,32,32]
    const float* __restrict__ gB,      // [8,32,32]
    const float* __restrict__ gC,      // [8,16,32]
    const float* __restrict__ g_logQ,  // [32]
    const float* __restrict__ g_logR,  // [16]
    const float* __restrict__ g_z0m,   // [32]
    const float* __restrict__ g_z0lv,  // [32]
    float* __restrict__ out)           // [B,T,2112]
{
    const int b   = blockIdx.x;
    const int tid = threadIdx.x;
    const int ri  = tid >> 3;        // 0..31
    const int cj  = (tid & 7) * 4;   // 0,4,...,28
    const size_t obase = (size_t)b * T_ * OSTRIDE;

    __shared__ __align__(16) float Amix[Z_][ZS];
    __shared__ __align__(16) float AmixT[Z_][ZS];
    __shared__ __align__(16) float Cmix[AD_][ZS];
    __shared__ __align__(16) float CmixT[Z_][CTS];
    __shared__ __align__(16) float zc[Z_][ZS];    // filtered cov / Ps in backward
    __shared__ __align__(16) float Tmp[Z_][ZS];   // A@zc   / D = Ps - Pp
    __shared__ __align__(16) float zcp[Z_][ZS];   // pred cov / JD
    __shared__ __align__(16) float CP[AD_][ZS];   // C @ zc_pred
    __shared__ __align__(16) float aug[Z_][AW];   // GJ32: [Pp | A@fc]
    __shared__ __align__(16) float aug16[AD_][A16W]; // GJ16: [S | CP]
    __shared__ __align__(16) float Ppb[Z_][ZS];
    __shared__ __align__(16) float fcb[Z_][ZS];
    __shared__ __align__(16) float alpha_s[K_];
    __shared__ __align__(16) float u_s[Z_];
    __shared__ __align__(16) float a_s[AD_];
    __shared__ __align__(16) float zm[Z_];
    __shared__ __align__(16) float zmp[Z_];
    __shared__ __align__(16) float resid[AD_];
    __shared__ __align__(16) float expQ[Z_];
    __shared__ __align__(16) float expR[AD_];
    __shared__ __align__(16) float vbuf[K_][33];
    __shared__ __align__(16) float fmb[Z_];
    __shared__ __align__(16) float zpb[Z_];
    __shared__ __align__(16) float dvec[Z_];
    __shared__ __align__(16) float prow[64];
    __shared__ __align__(16) float pcol[Z_];

    // ---- preload constant matrices into registers ----
    f4 rA[K_], rB[K_], rC[K_];
    {
        #pragma unroll
        for (int k = 0; k < K_; ++k)
            rA[k] = g4(gA + ((k * Z_ + ri) * Z_ + cj));
        const int kb = tid >> 5, ib = tid & 31;
        #pragma unroll
        for (int j4 = 0; j4 < K_; ++j4)
            rB[j4] = g4(gB + ((kb * Z_ + ib) * Z_ + j4 * 4));
        if (tid < 128) {
            const int ic = tid >> 3;
            #pragma unroll
            for (int k = 0; k < K_; ++k)
                rC[k] = g4(gC + ((k * AD_ + ic) * Z_ + cj));
        } else {
            #pragma unroll
            for (int k = 0; k < K_; ++k) rC[k] = zero4();
        }
    }

    // ---- init scalars + t=0 inputs ----
    if (tid < Z_)  expQ[tid] = expf(g_logQ[tid]);
    if (tid < AD_) expR[tid] = expf(g_logR[tid]);
    if (tid < K_)  alpha_s[tid] = g_alpha[(size_t)b * T_ * K_ + tid];
    if (tid < Z_)  u_s[tid] = g_u[(size_t)b * T_ * Z_ + tid];
    if (tid < AD_) a_s[tid] = g_a[(size_t)b * T_ * AD_ + tid];
    __syncthreads();

    // ================= FORWARD FILTER =================
    for (int t = 0; t < T_; ++t) {
        // prefetch next step's inputs into registers
        f4 pal = zero4(), pu = zero4(), pa = zero4();
        if (t + 1 < T_) {
            if (tid < 2)
                pal = g4(g_alpha + ((size_t)b * T_ + t + 1) * K_ + tid * 4);
            else if (tid >= 8 && tid < 16)
                pu = g4(g_u + ((size_t)b * T_ + t + 1) * Z_ + (tid - 8) * 4);
            else if (tid >= 16 && tid < 20)
                pa = g4(g_a + ((size_t)b * T_ + t + 1) * AD_ + (tid - 16) * 4);
        }

        // ---- Phase 1: mixtures ----
        if (t > 0) {
            f4 acc = zero4();
            #pragma unroll
            for (int k = 0; k < K_; ++k) acc = fma4(alpha_s[k], rA[k], acc);
            s4(&Amix[ri][cj], acc);
            AmixT[cj + 0][ri] = acc.x; AmixT[cj + 1][ri] = acc.y;
            AmixT[cj + 2][ri] = acc.z; AmixT[cj + 3][ri] = acc.w;
            {   // v_k[i] = (B_k @ u)[i]
                const int kb = tid >> 5, ib = tid & 31;
                float s = 0.f;
                #pragma unroll
                for (int j4 = 0; j4 < 8; ++j4) {
                    f4 bv = rB[j4];
                    s = fmaf(bv.x, u_s[j4 * 4 + 0], s);
                    s = fmaf(bv.y, u_s[j4 * 4 + 1], s);
                    s = fmaf(bv.z, u_s[j4 * 4 + 2], s);
                    s = fmaf(bv.w, u_s[j4 * 4 + 3], s);
                }
                vbuf[kb][ib] = s;
            }
        }
        if (tid < 128) {  // C mixture (needed every t)
            f4 acc = zero4();
            #pragma unroll
            for (int k = 0; k < K_; ++k) acc = fma4(alpha_s[k], rC[k], acc);
            s4(&Cmix[ri][cj], acc);
            CmixT[cj + 0][ri] = acc.x; CmixT[cj + 1][ri] = acc.y;
            CmixT[cj + 2][ri] = acc.z; CmixT[cj + 3][ri] = acc.w;
        }
        __syncthreads();

        // ---- Phase 2: predict ----
        if (t > 0) {
            if (tid < Z_) {
                float bu = 0.f;
                #pragma unroll
                for (int k = 0; k < K_; ++k) bu = fmaf(alpha_s[k], vbuf[k][tid], bu);
                float s = bu;
                #pragma unroll
                for (int m = 0; m < Z_; ++m) s = fmaf(Amix[tid][m], zm[m], s);
                zmp[tid] = s;
            }
            {   // Tmp = Amix @ zc
                f4 acc = zero4();
                #pragma unroll
                for (int m = 0; m < Z_; ++m)
                    acc = fma4(Amix[ri][m], g4(&zc[m][cj]), acc);
                s4(&Tmp[ri][cj], acc);
            }
            __syncthreads();
            {   // zcp = Tmp @ Amix^T + Q
                f4 acc = zero4();
                #pragma unroll
                for (int m = 0; m < Z_; ++m)
                    acc = fma4(Tmp[ri][m], g4(&AmixT[m][cj]), acc);
                if (ri == cj + 0) acc.x += expQ[ri];
                if (ri == cj + 1) acc.y += expQ[ri];
                if (ri == cj + 2) acc.z += expQ[ri];
                if (ri == cj + 3) acc.w += expQ[ri];
                s4(&zcp[ri][cj], acc);
                // save P_pred[t] into smoothed-cov slot (t-1) for the backward pass
                s4(out + obase + (size_t)(t - 1) * OSTRIDE + OFF_SC + ri * Z_ + cj, acc);
            }
        } else {
            // t == 0: zcp = diag(exp z0lv), zmp = z0_mean
            f4 acc = zero4();
            float ev = expf(g_z0lv[ri]);
            if (ri == cj + 0) acc.x = ev;
            if (ri == cj + 1) acc.y = ev;
            if (ri == cj + 2) acc.z = ev;
            if (ri == cj + 3) acc.w = ev;
            s4(&zcp[ri][cj], acc);
            if (tid < Z_) zmp[tid] = g_z0m[tid];
        }
        __syncthreads();

        // ---- Phase 3: CP = Cmix @ zcp ; a_pred/resid ; save z_pred ----
        if (tid < 128) {
            f4 acc = zero4();
            #pragma unroll
            for (int m = 0; m < Z_; ++m)
                acc = fma4(Cmix[ri][m], g4(&zcp[m][cj]), acc);
            s4(&CP[ri][cj], acc);
        } else if (tid < 128 + AD_) {
            const int i = tid - 128;
            float s = 0.f;
            #pragma unroll
            for (int m = 0; m < Z_; ++m) s = fmaf(Cmix[i][m], zmp[m], s);
            resid[i] = a_s[i] - s;
        } else if (t > 0 && tid >= 232 && tid < 240) {
            const int q = tid - 232;
            s4(out + obase + (size_t)(t - 1) * OSTRIDE + OFF_SM + q * 4, g4(&zmp[q * 4]));
        }
        __syncthreads();

        // ---- Phase 4: S = CP@Cmix^T + R ; build aug16 = [S | CP] ----
        {
            const int si = tid >> 4, sj = tid & 15;
            float s = (si == sj) ? expR[si] : 0.f;
            #pragma unroll
            for (int m = 0; m < Z_; ++m) s = fmaf(CP[si][m], Cmix[sj][m], s);
            aug16[si][sj] = s;
            const int c2 = sj * 2;
            aug16[si][16 + c2] = CP[si][c2];
            aug16[si][16 + c2 + 1] = CP[si][c2 + 1];
        }
        __syncthreads();

        // ---- Phase 5: GJ16 solve S * Kg^T = CP  (single wave, lockstep) ----
        if (tid < 64) {
            const int r = tid >> 2, cq = tid & 3;
            #pragma unroll 1
            for (int p = 0; p < AD_; ++p) {
                const float pinv = 1.0f / aug16[p][p];
                const float pc = aug16[r][p];
                float pr[12];
                #pragma unroll
                for (int cc = 0; cc < 12; ++cc) pr[cc] = aug16[p][cq * 12 + cc];
                #pragma unroll
                for (int cc = 0; cc < 12; ++cc) {
                    const float v = pr[cc] * pinv;
                    aug16[r][cq * 12 + cc] =
                        (r == p) ? v : fmaf(-pc, v, aug16[r][cq * 12 + cc]);
                }
            }
        }
        __syncthreads();

        // ---- Phase 6: measurement update ----
        {
            f4 acc = g4(&zcp[ri][cj]);
            #pragma unroll
            for (int k = 0; k < AD_; ++k)
                acc = fnma4(aug16[k][16 + ri], g4(&CP[k][cj]), acc);
            s4(&zc[ri][cj], acc);
            s4(out + obase + (size_t)t * OSTRIDE + OFF_FC + ri * Z_ + cj, acc);
        }
        if (tid < Z_) {
            float s = zmp[tid];
            #pragma unroll
            for (int k = 0; k < AD_; ++k) s = fmaf(aug16[k][16 + tid], resid[k], s);
            zm[tid] = s;
        }
        __syncthreads();
        if (tid < 8)
            s4(out + obase + (size_t)t * OSTRIDE + OFF_FM + tid * 4, g4(&zm[tid * 4]));
        // commit prefetched inputs
        if (t + 1 < T_) {
            if (tid < 2)                    s4(&alpha_s[tid * 4], pal);
            else if (tid >= 8 && tid < 16)  s4(&u_s[(tid - 8) * 4], pu);
            else if (tid >= 16 && tid < 20) s4(&a_s[(tid - 16) * 4], pa);
        }
        __syncthreads();
    }

    // ================= SMOOTHER INIT =================
    // smoothed[T-1] = filtered[T-1] (zm/zc still hold them)
    s4(out + obase + (size_t)(T_ - 1) * OSTRIDE + OFF_SC + ri * Z_ + cj, g4(&zc[ri][cj]));
    if (tid < 8)
        s4(out + obase + (size_t)(T_ - 1) * OSTRIDE + OFF_SM + tid * 4, g4(&zm[tid * 4]));
    // load buffers for t = T-2
    {
        const float* slot = out + obase + (size_t)(T_ - 2) * OSTRIDE;
        s4(&Ppb[ri][cj], g4(slot + OFF_SC + ri * Z_ + cj));
        s4(&fcb[ri][cj], g4(slot + OFF_FC + ri * Z_ + cj));
        if (tid < 8)                    s4(&zpb[tid * 4], g4(slot + OFF_SM + tid * 4));
        else if (tid >= 8 && tid < 16)  s4(&fmb[(tid - 8) * 4], g4(slot + OFF_FM + (tid - 8) * 4));
        else if (tid >= 16 && tid < 18)
            s4(&alpha_s[(tid - 16) * 4],
               g4(g_alpha + ((size_t)b * T_ + (T_ - 1)) * K_ + (tid - 16) * 4));
    }
    __syncthreads();

    // ================= BACKWARD SMOOTHER =================
    for (int t = T_ - 2; t >= 0; --t) {
        // prefetch slot (t-1)
        f4 ppp = zero4(), pfc = zero4(), pzp = zero4(), pfm = zero4(), pal2 = zero4();
        if (t > 0) {
            const float* slot = out + obase + (size_t)(t - 1) * OSTRIDE;
            ppp = g4(slot + OFF_SC + ri * Z_ + cj);
            pfc = g4(slot + OFF_FC + ri * Z_ + cj);
            if (tid < 8)                    pzp = g4(slot + OFF_SM + tid * 4);
            else if (tid >= 8 && tid < 16)  pfm = g4(slot + OFF_FM + (tid - 8) * 4);
            else if (tid >= 16 && tid < 18)
                pal2 = g4(g_alpha + ((size_t)b * T_ + t) * K_ + (tid - 16) * 4);
        }

        // ---- B1: A-mix (= A_{t+1}); D = Ps - Pp; aug left = Pp; dvec ----
        {
            f4 acc = zero4();
            #pragma unroll
            for (int k = 0; k < K_; ++k) acc = fma4(alpha_s[k], rA[k], acc);
            s4(&Amix[ri][cj], acc);
            f4 pp4 = g4(&Ppb[ri][cj]);
            s4(&Tmp[ri][cj], sub4(g4(&zc[ri][cj]), pp4));
            s4(&aug[ri][cj], pp4);
        }
        if (tid < Z_) dvec[tid] = zm[tid] - zpb[tid];
        __syncthreads();

        // ---- B2: aug right = A_{t+1} @ fc  (= (fc A^T)^T) ----
        {
            f4 acc = zero4();
            #pragma unroll
            for (int m = 0; m < Z_; ++m)
                acc = fma4(Amix[ri][m], g4(&fcb[m][cj]), acc);
            s4(&aug[ri][32 + cj], acc);
        }
        __syncthreads();

        // ---- B3: GJ32 solve Pp * J^T = (A fc)  -> right half = J^T ----
        #pragma unroll 1
        for (int p = 0; p < Z_; ++p) {
            if (tid < 64) {
                const float pinv = 1.0f / aug[p][p];
                prow[tid] = aug[p][tid] * pinv;
            } else if (tid < 96) {
                pcol[tid - 64] = aug[tid - 64][p];
            }
            __syncthreads();
            {
                const int r = tid >> 3, c0 = (tid & 7) * 8;
                const float pc = pcol[r];
                f4 p0 = g4(&prow[c0]), p1 = g4(&prow[c0 + 4]);
                f4 v0 = fnma4(pc, p0, g4(&aug[r][c0]));
                f4 v1 = fnma4(pc, p1, g4(&aug[r][c0 + 4]));
                if (r == p) { v0 = p0; v1 = p1; }
                s4(&aug[r][c0], v0);
                s4(&aug[r][c0 + 4], v1);
            }
            __syncthreads();
        }

        // ---- B4: JD = J @ D ; zs update ----
        {
            f4 acc = zero4();
            #pragma unroll
            for (int l = 0; l < Z_; ++l)
                acc = fma4(aug[l][32 + ri], g4(&Tmp[l][cj]), acc);
            s4(&zcp[ri][cj], acc);
        }
        if (tid < Z_) {
            float s = fmb[tid];
            #pragma unroll
            for (int l = 0; l < Z_; ++l) s = fmaf(aug[l][32 + tid], dvec[l], s);
            zm[tid] = s;
        }
        __syncthreads();

        // ---- B5: Ps_new = fc + JD @ J^T ; write smoothed ----
        {
            f4 acc = g4(&fcb[ri][cj]);
            #pragma unroll
            for (int l = 0; l < Z_; ++l)
                acc = fma4(zcp[ri][l], g4(&aug[l][32 + cj]), acc);
            s4(&zc[ri][cj], acc);
            s4(out + obase + (size_t)t * OSTRIDE + OFF_SC + ri * Z_ + cj, acc);
        }
        if (tid < 8)
            s4(out + obase + (size_t)t * OSTRIDE + OFF_SM + tid * 4, g4(&zm[tid * 4]));
        __syncthreads();

        // ---- B6: commit prefetched buffers ----
        if (t > 0) {
            s4(&Ppb[ri][cj], ppp);
            s4(&fcb[ri][cj], pfc);
            if (tid < 8)                    s4(&zpb[tid * 4], pzp);
            else if (tid >= 8 && tid < 16)  s4(&fmb[(tid - 8) * 4], pfm);
            else if (tid >= 16 && tid < 18) s4(&alpha_s[(tid - 16) * 4], pal2);
        }
        __syncthreads();
    }
}

extern "C" void kernel_launch(void* const* d_in, const int* in_sizes, int n_in,
                              void* d_out, int out_size, void* d_ws, size_t ws_size,
                              hipStream_t stream) {
    const float* a_obs = (const float*)d_in[0];
    const float* alpha = (const float*)d_in[1];
    const float* u     = (const float*)d_in[2];
    const float* A_m   = (const float*)d_in[3];
    const float* B_m   = (const float*)d_in[4];
    const float* C_m   = (const float*)d_in[5];
    const float* logQ  = (const float*)d_in[6];
    const float* logR  = (const float*)d_in[7];
    const float* z0m   = (const float*)d_in[8];
    const float* z0lv  = (const float*)d_in[9];
    (void)in_sizes; (void)n_in; (void)out_size; (void)d_ws; (void)ws_size;

    kalman<<<dim3(B_), dim3(256), 0, stream>>>(
        a_obs, alpha, u, A_m, B_m, C_m, logQ, logR, z0m, z0lv, (float*)d_out);
}

// Round 3
// 7447.363 us; speedup vs baseline: 1.4276x; 1.4276x over previous
//
#include <hip/hip_runtime.h>
#include <math.h>

#define B_   128
#define T_   512
#define Z_   32
#define AD_  16
#define K_   8

#define OSTRIDE 2112   // per (b,t): fm(32) fc(1024) sm(32) sc(1024)
#define OFF_FM  0
#define OFF_FC  32
#define OFF_SM  1056
#define OFF_SC  1088

#define ZS   36   // padded row stride for 32-wide LDS rows
#define AW   68   // GJ32 augmented stride
#define A16W 52   // GJ16 augmented stride

typedef float4 f4;

__device__ __forceinline__ f4 g4(const float* p) { return *reinterpret_cast<const f4*>(p); }
__device__ __forceinline__ void s4(float* p, f4 v) { *reinterpret_cast<f4*>(p) = v; }
__device__ __forceinline__ f4 zero4() { return make_float4(0.f, 0.f, 0.f, 0.f); }
__device__ __forceinline__ f4 fma4(float a, f4 b, f4 c) {
    c.x = fmaf(a, b.x, c.x); c.y = fmaf(a, b.y, c.y);
    c.z = fmaf(a, b.z, c.z); c.w = fmaf(a, b.w, c.w);
    return c;
}
__device__ __forceinline__ f4 fnma4(float a, f4 b, f4 c) {  // c - a*b
    c.x = fmaf(-a, b.x, c.x); c.y = fmaf(-a, b.y, c.y);
    c.z = fmaf(-a, b.z, c.z); c.w = fmaf(-a, b.w, c.w);
    return c;
}
__device__ __forceinline__ f4 sub4(f4 a, f4 b) {
    return make_float4(a.x - b.x, a.y - b.y, a.z - b.z, a.w - b.w);
}

// ============================================================================
// Kernel 1: forward filter (serial over T, one block per batch element).
// Writes fm/fc; stashes P_pred[t+1] -> sc[t], z_pred[t+1] -> sm[t];
// writes smoothed[T-1] = filtered[T-1].
// ============================================================================
__global__ __launch_bounds__(256, 1) void fwd(
    const float* __restrict__ g_a,     // [B,T,16]
    const float* __restrict__ g_alpha, // [B,T,8]
    const float* __restrict__ g_u,     // [B,T,32]
    const float* __restrict__ gA,      // [8,32,32]
    const float* __restrict__ gB,      // [8,32,32]
    const float* __restrict__ gC,      // [8,16,32]
    const float* __restrict__ g_logQ,  // [32]
    const float* __restrict__ g_logR,  // [16]
    const float* __restrict__ g_z0m,   // [32]
    const float* __restrict__ g_z0lv,  // [32]
    float* __restrict__ out)           // [B,T,2112]
{
    const int b   = blockIdx.x;
    const int tid = threadIdx.x;
    const int ri  = tid >> 3;        // 0..31
    const int cj  = (tid & 7) * 4;   // 0,4,...,28
    const size_t obase = (size_t)b * T_ * OSTRIDE;

    __shared__ __align__(16) float Amix[Z_][ZS];
    __shared__ __align__(16) float AmixT[Z_][ZS];
    __shared__ __align__(16) float Cmix[AD_][ZS];
    __shared__ __align__(16) float zc[Z_][ZS];
    __shared__ __align__(16) float Tmp[Z_][ZS];
    __shared__ __align__(16) float zcp[Z_][ZS];
    __shared__ __align__(16) float CP[AD_][ZS];
    __shared__ __align__(16) float aug16[AD_][A16W];
    __shared__ __align__(16) float alpha_s[K_];
    __shared__ __align__(16) float u_s[Z_];
    __shared__ __align__(16) float a_s[AD_];
    __shared__ __align__(16) float zm[Z_];
    __shared__ __align__(16) float zmp[Z_];
    __shared__ __align__(16) float resid[AD_];
    __shared__ __align__(16) float expQ[Z_];
    __shared__ __align__(16) float expR[AD_];
    __shared__ __align__(16) float vbuf[K_][33];

    // preload constant matrices into registers
    f4 rA[K_], rB[K_], rC[K_];
    {
        #pragma unroll
        for (int k = 0; k < K_; ++k)
            rA[k] = g4(gA + ((k * Z_ + ri) * Z_ + cj));
        const int kb = tid >> 5, ib = tid & 31;
        #pragma unroll
        for (int j4 = 0; j4 < K_; ++j4)
            rB[j4] = g4(gB + ((kb * Z_ + ib) * Z_ + j4 * 4));
        if (tid < 128) {
            const int ic = tid >> 3;
            #pragma unroll
            for (int k = 0; k < K_; ++k)
                rC[k] = g4(gC + ((k * AD_ + ic) * Z_ + cj));
        } else {
            #pragma unroll
            for (int k = 0; k < K_; ++k) rC[k] = zero4();
        }
    }

    if (tid < Z_)  expQ[tid] = expf(g_logQ[tid]);
    if (tid < AD_) expR[tid] = expf(g_logR[tid]);
    if (tid < K_)  alpha_s[tid] = g_alpha[(size_t)b * T_ * K_ + tid];
    if (tid < Z_)  u_s[tid] = g_u[(size_t)b * T_ * Z_ + tid];
    if (tid < AD_) a_s[tid] = g_a[(size_t)b * T_ * AD_ + tid];
    __syncthreads();

    for (int t = 0; t < T_; ++t) {
        f4 pal = zero4(), pu = zero4(), pa = zero4();
        if (t + 1 < T_) {
            if (tid < 2)
                pal = g4(g_alpha + ((size_t)b * T_ + t + 1) * K_ + tid * 4);
            else if (tid >= 8 && tid < 16)
                pu = g4(g_u + ((size_t)b * T_ + t + 1) * Z_ + (tid - 8) * 4);
            else if (tid >= 16 && tid < 20)
                pa = g4(g_a + ((size_t)b * T_ + t + 1) * AD_ + (tid - 16) * 4);
        }

        // Phase 1: mixtures
        if (t > 0) {
            f4 acc = zero4();
            #pragma unroll
            for (int k = 0; k < K_; ++k) acc = fma4(alpha_s[k], rA[k], acc);
            s4(&Amix[ri][cj], acc);
            AmixT[cj + 0][ri] = acc.x; AmixT[cj + 1][ri] = acc.y;
            AmixT[cj + 2][ri] = acc.z; AmixT[cj + 3][ri] = acc.w;
            {   // v_k[i] = (B_k @ u)[i]
                const int kb = tid >> 5, ib = tid & 31;
                float s = 0.f;
                #pragma unroll
                for (int j4 = 0; j4 < 8; ++j4) {
                    f4 bv = rB[j4];
                    s = fmaf(bv.x, u_s[j4 * 4 + 0], s);
                    s = fmaf(bv.y, u_s[j4 * 4 + 1], s);
                    s = fmaf(bv.z, u_s[j4 * 4 + 2], s);
                    s = fmaf(bv.w, u_s[j4 * 4 + 3], s);
                }
                vbuf[kb][ib] = s;
            }
        }
        if (tid < 128) {  // C mixture
            f4 acc = zero4();
            #pragma unroll
            for (int k = 0; k < K_; ++k) acc = fma4(alpha_s[k], rC[k], acc);
            s4(&Cmix[ri][cj], acc);
        }
        __syncthreads();

        // Phase 2: predict
        if (t > 0) {
            if (tid < Z_) {
                float bu = 0.f;
                #pragma unroll
                for (int k = 0; k < K_; ++k) bu = fmaf(alpha_s[k], vbuf[k][tid], bu);
                float s = bu;
                #pragma unroll
                for (int m = 0; m < Z_; ++m) s = fmaf(Amix[tid][m], zm[m], s);
                zmp[tid] = s;
            }
            {   // Tmp = Amix @ zc
                f4 acc = zero4();
                #pragma unroll
                for (int m = 0; m < Z_; ++m)
                    acc = fma4(Amix[ri][m], g4(&zc[m][cj]), acc);
                s4(&Tmp[ri][cj], acc);
            }
            __syncthreads();
            {   // zcp = Tmp @ Amix^T + Q
                f4 acc = zero4();
                #pragma unroll
                for (int m = 0; m < Z_; ++m)
                    acc = fma4(Tmp[ri][m], g4(&AmixT[m][cj]), acc);
                if (ri == cj + 0) acc.x += expQ[ri];
                if (ri == cj + 1) acc.y += expQ[ri];
                if (ri == cj + 2) acc.z += expQ[ri];
                if (ri == cj + 3) acc.w += expQ[ri];
                s4(&zcp[ri][cj], acc);
                // stash P_pred[t] into sc[t-1] for jkern/bwd
                s4(out + obase + (size_t)(t - 1) * OSTRIDE + OFF_SC + ri * Z_ + cj, acc);
            }
        } else {
            f4 acc = zero4();
            float ev = expf(g_z0lv[ri]);
            if (ri == cj + 0) acc.x = ev;
            if (ri == cj + 1) acc.y = ev;
            if (ri == cj + 2) acc.z = ev;
            if (ri == cj + 3) acc.w = ev;
            s4(&zcp[ri][cj], acc);
            if (tid < Z_) zmp[tid] = g_z0m[tid];
        }
        __syncthreads();

        // Phase 3: CP = Cmix @ zcp ; resid ; stash z_pred
        if (tid < 128) {
            f4 acc = zero4();
            #pragma unroll
            for (int m = 0; m < Z_; ++m)
                acc = fma4(Cmix[ri][m], g4(&zcp[m][cj]), acc);
            s4(&CP[ri][cj], acc);
        } else if (tid < 128 + AD_) {
            const int i = tid - 128;
            float s = 0.f;
            #pragma unroll
            for (int m = 0; m < Z_; ++m) s = fmaf(Cmix[i][m], zmp[m], s);
            resid[i] = a_s[i] - s;
        } else if (t > 0 && tid >= 232 && tid < 240) {
            const int q = tid - 232;
            s4(out + obase + (size_t)(t - 1) * OSTRIDE + OFF_SM + q * 4, g4(&zmp[q * 4]));
        }
        __syncthreads();

        // Phase 4: S = CP@Cmix^T + R ; aug16 = [S | CP]
        {
            const int si = tid >> 4, sj = tid & 15;
            float s = (si == sj) ? expR[si] : 0.f;
            #pragma unroll
            for (int m = 0; m < Z_; ++m) s = fmaf(CP[si][m], Cmix[sj][m], s);
            aug16[si][sj] = s;
            const int c2 = sj * 2;
            aug16[si][16 + c2] = CP[si][c2];
            aug16[si][16 + c2 + 1] = CP[si][c2 + 1];
        }
        __syncthreads();

        // Phase 5: GJ16 solve S * Kg^T = CP (single wave, lockstep)
        if (tid < 64) {
            const int r = tid >> 2, cq = tid & 3;
            #pragma unroll 1
            for (int p = 0; p < AD_; ++p) {
                const float pinv = 1.0f / aug16[p][p];
                const float pc = aug16[r][p];
                float pr[12];
                #pragma unroll
                for (int cc = 0; cc < 12; ++cc) pr[cc] = aug16[p][cq * 12 + cc];
                #pragma unroll
                for (int cc = 0; cc < 12; ++cc) {
                    const float v = pr[cc] * pinv;
                    aug16[r][cq * 12 + cc] =
                        (r == p) ? v : fmaf(-pc, v, aug16[r][cq * 12 + cc]);
                }
            }
        }
        __syncthreads();

        // Phase 6: measurement update
        {
            f4 acc = g4(&zcp[ri][cj]);
            #pragma unroll
            for (int k = 0; k < AD_; ++k)
                acc = fnma4(aug16[k][16 + ri], g4(&CP[k][cj]), acc);
            s4(&zc[ri][cj], acc);
            s4(out + obase + (size_t)t * OSTRIDE + OFF_FC + ri * Z_ + cj, acc);
        }
        if (tid < Z_) {
            float s = zmp[tid];
            #pragma unroll
            for (int k = 0; k < AD_; ++k) s = fmaf(aug16[k][16 + tid], resid[k], s);
            zm[tid] = s;
        }
        __syncthreads();
        if (tid < 8)
            s4(out + obase + (size_t)t * OSTRIDE + OFF_FM + tid * 4, g4(&zm[tid * 4]));
        if (t + 1 < T_) {
            if (tid < 2)                    s4(&alpha_s[tid * 4], pal);
            else if (tid >= 8 && tid < 16)  s4(&u_s[(tid - 8) * 4], pu);
            else if (tid >= 16 && tid < 20) s4(&a_s[(tid - 16) * 4], pa);
        }
        __syncthreads();
    }

    // smoothed[T-1] = filtered[T-1]
    s4(out + obase + (size_t)(T_ - 1) * OSTRIDE + OFF_SC + ri * Z_ + cj, g4(&zc[ri][cj]));
    if (tid < 8)
        s4(out + obase + (size_t)(T_ - 1) * OSTRIDE + OFF_SM + tid * 4, g4(&zm[tid * 4]));
}

// ============================================================================
// Kernel 2: parallel smoother-gain. One block per (b,t), t in [0, T-2].
// Solves Pp_{t+1} * J^T = A_{t+1} @ fc_t  (GJ32), computes m_t = fm - J zp.
// Overwrites sc[t] <- J^T (row-major Jt[l][i] = J[i][l]), sm[t] <- m.
// ============================================================================
__global__ __launch_bounds__(256, 1) void jkern(
    const float* __restrict__ g_alpha,
    const float* __restrict__ gA,
    float* __restrict__ out)
{
    const int t   = blockIdx.x;      // 0..T-2
    const int b   = blockIdx.y;
    const int tid = threadIdx.x;
    const int ri  = tid >> 3;
    const int cj  = (tid & 7) * 4;
    float* slot = out + ((size_t)b * T_ + t) * OSTRIDE;

    __shared__ __align__(16) float Amix[Z_][ZS];
    __shared__ __align__(16) float fcb[Z_][ZS];
    __shared__ __align__(16) float aug[Z_][AW];
    __shared__ __align__(16) float prow[64];
    __shared__ __align__(16) float pcol[Z_];
    __shared__ __align__(16) float alpha_s[K_];
    __shared__ __align__(16) float zp[Z_];
    __shared__ __align__(16) float fmv[Z_];
    __shared__ __align__(16) float mvec[Z_];

    if (tid < K_) alpha_s[tid] = g_alpha[((size_t)b * T_ + t + 1) * K_ + tid];
    s4(&fcb[ri][cj], g4(slot + OFF_FC + ri * Z_ + cj));
    s4(&aug[ri][cj], g4(slot + OFF_SC + ri * Z_ + cj));   // Pp_{t+1}
    if (tid >= 32 && tid < 64)       zp[tid - 32]  = slot[OFF_SM + (tid - 32)];
    else if (tid >= 64 && tid < 96)  fmv[tid - 64] = slot[OFF_FM + (tid - 64)];
    __syncthreads();

    {   // Amix = sum_k alpha_k A_k
        f4 acc = zero4();
        #pragma unroll
        for (int k = 0; k < K_; ++k)
            acc = fma4(alpha_s[k], g4(gA + ((k * Z_ + ri) * Z_ + cj)), acc);
        s4(&Amix[ri][cj], acc);
    }
    __syncthreads();
    {   // RHS = Amix @ fc
        f4 acc = zero4();
        #pragma unroll
        for (int m = 0; m < Z_; ++m)
            acc = fma4(Amix[ri][m], g4(&fcb[m][cj]), acc);
        s4(&aug[ri][32 + cj], acc);
    }
    __syncthreads();

    // GJ32: Pp * X = RHS  ->  right half = X = J^T
    #pragma unroll 1
    for (int p = 0; p < Z_; ++p) {
        if (tid < 64) {
            const float pinv = 1.0f / aug[p][p];
            prow[tid] = aug[p][tid] * pinv;
        } else if (tid < 96) {
            pcol[tid - 64] = aug[tid - 64][p];
        }
        __syncthreads();
        {
            const int r = tid >> 3, c0 = (tid & 7) * 8;
            const float pc = pcol[r];
            f4 p0 = g4(&prow[c0]), p1 = g4(&prow[c0 + 4]);
            f4 v0 = fnma4(pc, p0, g4(&aug[r][c0]));
            f4 v1 = fnma4(pc, p1, g4(&aug[r][c0 + 4]));
            if (r == p) { v0 = p0; v1 = p1; }
            s4(&aug[r][c0], v0);
            s4(&aug[r][c0 + 4], v1);
        }
        __syncthreads();
    }

    // m = fm - J zp : m[i] = fm[i] - sum_l Jt[l][i] * zp[l]
    if (tid < Z_) {
        float s = fmv[tid];
        #pragma unroll
        for (int l = 0; l < Z_; ++l) s = fmaf(-aug[l][32 + tid], zp[l], s);
        mvec[tid] = s;
    }
    __syncthreads();

    // write Jt (row-major) into sc[t], m into sm[t]
    s4(slot + OFF_SC + ri * Z_ + cj, g4(&aug[ri][32 + cj]));
    if (tid < 8) s4(slot + OFF_SM + tid * 4, g4(&mvec[tid * 4]));
}

// ============================================================================
// Kernel 3: serial backward smoother. One block per batch element.
// Per step: Pp = A fc A^T + Q (bitwise-identical to fwd), D = Ps - Pp,
// H = J D, Ps' = fc + H J^T, zs' = m + J zs. 6 barriers/step.
// ============================================================================
__global__ __launch_bounds__(256, 1) void bwd(
    const float* __restrict__ g_alpha,
    const float* __restrict__ gA,
    const float* __restrict__ g_logQ,
    float* __restrict__ out)
{
    const int b   = blockIdx.x;
    const int tid = threadIdx.x;
    const int ri  = tid >> 3;
    const int cj  = (tid & 7) * 4;
    const size_t obase = (size_t)b * T_ * OSTRIDE;

    __shared__ __align__(16) float Amix[Z_][ZS];
    __shared__ __align__(16) float AmixT[Z_][ZS];
    __shared__ __align__(16) float Jt[Z_][ZS];    // Jt[l][i] = J[i][l]
    __shared__ __align__(16) float fcb[Z_][ZS];
    __shared__ __align__(16) float Tmp[Z_][ZS];
    __shared__ __align__(16) float Dm[Z_][ZS];
    __shared__ __align__(16) float Ps[Z_][ZS];
    __shared__ __align__(16) float alpha_s[K_];
    __shared__ __align__(16) float mvec[Z_];
    __shared__ __align__(16) float zs[Z_];
    __shared__ __align__(16) float zsn[Z_];
    __shared__ __align__(16) float expQ[Z_];

    f4 rA[K_];
    #pragma unroll
    for (int k = 0; k < K_; ++k) rA[k] = g4(gA + ((k * Z_ + ri) * Z_ + cj));
    if (tid < Z_) expQ[tid] = expf(g_logQ[tid]);

    {   // carry = filtered[T-1]; load step T-2 data
        const float* slotF = out + obase + (size_t)(T_ - 1) * OSTRIDE;
        s4(&Ps[ri][cj], g4(slotF + OFF_FC + ri * Z_ + cj));
        if (tid >= 64 && tid < 96) zs[tid - 64] = slotF[OFF_FM + (tid - 64)];
        const float* slot = out + obase + (size_t)(T_ - 2) * OSTRIDE;
        s4(&Jt[ri][cj], g4(slot + OFF_SC + ri * Z_ + cj));
        s4(&fcb[ri][cj], g4(slot + OFF_FC + ri * Z_ + cj));
        if (tid < Z_) mvec[tid] = slot[OFF_SM + tid];
        if (tid >= 96 && tid < 104)
            alpha_s[tid - 96] = g_alpha[((size_t)b * T_ + (T_ - 1)) * K_ + (tid - 96)];
    }
    __syncthreads();

    for (int t = T_ - 2; t >= 0; --t) {
        // prefetch slot t-1
        f4 pJ = zero4(), pfc = zero4(); float pm = 0.f, pal = 0.f;
        if (t > 0) {
            const float* slot = out + obase + (size_t)(t - 1) * OSTRIDE;
            pJ  = g4(slot + OFF_SC + ri * Z_ + cj);
            pfc = g4(slot + OFF_FC + ri * Z_ + cj);
            if (tid < Z_) pm = slot[OFF_SM + tid];
            if (tid >= 96 && tid < 104)
                pal = g_alpha[((size_t)b * T_ + t) * K_ + (tid - 96)];
        }

        // B1: Amix/AmixT ; zsn = m + J zs
        {
            f4 acc = zero4();
            #pragma unroll
            for (int k = 0; k < K_; ++k) acc = fma4(alpha_s[k], rA[k], acc);
            s4(&Amix[ri][cj], acc);
            AmixT[cj + 0][ri] = acc.x; AmixT[cj + 1][ri] = acc.y;
            AmixT[cj + 2][ri] = acc.z; AmixT[cj + 3][ri] = acc.w;
        }
        if (tid >= 64 && tid < 96) {
            const int i = tid - 64;
            float s = mvec[i];
            #pragma unroll
            for (int l = 0; l < Z_; ++l) s = fmaf(Jt[l][i], zs[l], s);
            zsn[i] = s;
        }
        __syncthreads();

        // B2: Tmp = Amix @ fc
        {
            f4 acc = zero4();
            #pragma unroll
            for (int m = 0; m < Z_; ++m)
                acc = fma4(Amix[ri][m], g4(&fcb[m][cj]), acc);
            s4(&Tmp[ri][cj], acc);
        }
        __syncthreads();

        // B3: Pp = Tmp @ AmixT + Q ; D = Ps - Pp
        {
            f4 acc = zero4();
            #pragma unroll
            for (int m = 0; m < Z_; ++m)
                acc = fma4(Tmp[ri][m], g4(&AmixT[m][cj]), acc);
            if (ri == cj + 0) acc.x += expQ[ri];
            if (ri == cj + 1) acc.y += expQ[ri];
            if (ri == cj + 2) acc.z += expQ[ri];
            if (ri == cj + 3) acc.w += expQ[ri];
            s4(&Dm[ri][cj], sub4(g4(&Ps[ri][cj]), acc));
        }
        __syncthreads();

        // B4: H = J @ D  (H[i][j] = sum_l Jt[l][i] D[l][j]) -> reuse Amix
        {
            f4 acc = zero4();
            #pragma unroll
            for (int l = 0; l < Z_; ++l)
                acc = fma4(Jt[l][ri], g4(&Dm[l][cj]), acc);
            s4(&Amix[ri][cj], acc);
        }
        __syncthreads();

        // B5: Ps' = fc + H @ J^T (Ps'[i][j] = fc[i][j] + sum_l H[i][l] Jt[l][j])
        {
            f4 acc = g4(&fcb[ri][cj]);
            #pragma unroll
            for (int l = 0; l < Z_; ++l)
                acc = fma4(Amix[ri][l], g4(&Jt[l][cj]), acc);
            s4(&Ps[ri][cj], acc);
            s4(out + obase + (size_t)t * OSTRIDE + OFF_SC + ri * Z_ + cj, acc);
        }
        if (tid < 8)
            s4(out + obase + (size_t)t * OSTRIDE + OFF_SM + tid * 4, g4(&zsn[tid * 4]));
        else if (tid >= 64 && tid < 96)
            zs[tid - 64] = zsn[tid - 64];
        __syncthreads();

        // B6: commit prefetched buffers
        if (t > 0) {
            s4(&Jt[ri][cj], pJ);
            s4(&fcb[ri][cj], pfc);
            if (tid < Z_) mvec[tid] = pm;
            if (tid >= 96 && tid < 104) alpha_s[tid - 96] = pal;
        }
        __syncthreads();
    }
}

extern "C" void kernel_launch(void* const* d_in, const int* in_sizes, int n_in,
                              void* d_out, int out_size, void* d_ws, size_t ws_size,
                              hipStream_t stream) {
    const float* a_obs = (const float*)d_in[0];
    const float* alpha = (const float*)d_in[1];
    const float* u     = (const float*)d_in[2];
    const float* A_m   = (const float*)d_in[3];
    const float* B_m   = (const float*)d_in[4];
    const float* C_m   = (const float*)d_in[5];
    const float* logQ  = (const float*)d_in[6];
    const float* logR  = (const float*)d_in[7];
    const float* z0m   = (const float*)d_in[8];
    const float* z0lv  = (const float*)d_in[9];
    (void)in_sizes; (void)n_in; (void)out_size; (void)d_ws; (void)ws_size;
    float* out = (float*)d_out;

    fwd<<<dim3(B_), dim3(256), 0, stream>>>(
        a_obs, alpha, u, A_m, B_m, C_m, logQ, logR, z0m, z0lv, out);
    jkern<<<dim3(T_ - 1, B_), dim3(256), 0, stream>>>(alpha, A_m, out);
    bwd<<<dim3(B_), dim3(256), 0, stream>>>(alpha, A_m, logQ, out);
}